// Round 13
// baseline (48.950 us; speedup 1.0000x reference)
//
#include <hip/hip_runtime.h>
#include <hip/hip_bf16.h>

// loss_separation: X[n, b*2+c] = keypoints[b, n, c], N=8192 rows, K=128 cols.
// loss = sum_{i != j} exp(-0.4 * ||X_i - X_j||)
// Round 13 = Round 7 pair body EXACTLY (best: 31.9us) + structural cut:
//   - reduce kernel + its graph gap eliminated: each pair block does ONE
//     fire-and-forget device-scope atomicAdd(out, v). No fence / no acquire
//     / no spin (R8's poison was __threadfence, not the atomic RMW).
//   - out[0] zeroed via 4-byte hipMemsetAsync in-graph (R8-validated).
//   - prep = 512-block variant (validated R11/R12).
// Summation-order noise of 2080 fp32 atomics ~ tens; threshold 2.1e5.

#define N_KP   8192
#define KDIM   128          // B*C = 64*2
#define NT     64           // number of 128-row tiles
#define NTILES (NT * (NT + 1) / 2)   // 2080 upper-tri tiles
#define COEF2  (-0.57707801635558535f)   // -0.4 * log2(e)

typedef __attribute__((ext_vector_type(8))) short bf16x8;
typedef __attribute__((ext_vector_type(4))) float f32x4;

// Swizzled X layout (ushort units): fragment f = (rowblk16*4 + kk) holds the
// MFMA A/B fragment for rows [rowblk16*16, +16), k in [kk*32, +32):
//   Xs[f*512 + slot*8 + e], slot = (lane>>4)*16 + (lane&15)
//   = X[rowblk16*16 + (lane&15)][kk*32 + (lane>>4)*8 + e]
// One fragment = 1 KB, contiguous. A 128-row tile t = fragments [t*32, t*32+32).

__device__ __forceinline__ unsigned short f2bf(float f) {
    unsigned int u = __builtin_bit_cast(unsigned int, f);
    unsigned int r = (u + 0x7FFFu + ((u >> 16) & 1u)) >> 16;
    return (unsigned short)r;
}

__device__ __forceinline__ float bf2f(unsigned short u) {
    unsigned int x = ((unsigned int)u) << 16;
    return __builtin_bit_cast(float, x);
}

__device__ __forceinline__ void gload_lds16(const void* g, void* l) {
    __builtin_amdgcn_global_load_lds(
        (const __attribute__((address_space(1))) unsigned int*)g,
        (__attribute__((address_space(3))) unsigned int*)l, 16, 0, 0);
}

// 512 blocks x 256 threads; block handles 16 keypoints, thread handles 4 b's.
__global__ __launch_bounds__(256) void prep_kernel(
        const float* __restrict__ in, unsigned short* __restrict__ Xbf,
        float* __restrict__ sq) {
    int tid = threadIdx.x;
    int bt = tid >> 4, nl = tid & 15;       // 16 b-groups x 16 keypoints
    int n = blockIdx.x * 16 + nl;
    int t16 = n >> 4, l16 = n & 15;
    unsigned int* dst = (unsigned int*)Xbf;
    float s = 0.0f;
    #pragma unroll
    for (int q = 0; q < 4; ++q) {
        int b = bt * 4 + q;
        float2 v = *(const float2*)(in + (size_t)b * (N_KP * 2) + n * 2);
        unsigned short h0 = f2bf(v.x);
        unsigned short h1 = f2bf(v.y);
        float f0 = bf2f(h0), f1 = bf2f(h1);
        s = fmaf(f0, f0, s);
        s = fmaf(f1, f1, s);
        // k = 2b (+c): kk = b>>4, lhi = (b>>2)&3, e = (b&3)*2
        unsigned int off_us = (((unsigned)(t16 * 4 + (b >> 4)) * 64
                                + ((b >> 2) & 3) * 16 + l16) << 3) + ((b & 3) << 1);
        dst[off_us >> 1] = ((unsigned int)h1 << 16) | h0;
    }
    __shared__ float wsq[256];
    wsq[tid] = s;                            // [bt][nl]
    __syncthreads();
    if (tid < 16) {
        float t = 0.0f;
        #pragma unroll
        for (int pp = 0; pp < 16; ++pp) t += wsq[pp * 16 + tid];
        sq[blockIdx.x * 16 + tid] = t;
    }
}

__global__ __launch_bounds__(256, 4) void pair_kernel(
        const unsigned short* __restrict__ Xbf, const float* __restrict__ sq,
        float* __restrict__ out) {
    int bid = blockIdx.x;
    // decode (ti, tj), ti <= tj: off(t) = t*(129-t)/2 tiles precede row t.
    int ti = (int)((129.0f - sqrtf(129.0f * 129.0f - 8.0f * (float)bid)) * 0.5f);
    while (ti > 0 && ti * (129 - ti) / 2 > bid) --ti;
    while ((ti + 1) * (129 - (ti + 1)) / 2 <= bid) ++ti;
    int tj = ti + (bid - ti * (129 - ti) / 2);

    int wid  = threadIdx.x >> 6;
    int lane = threadIdx.x & 63;
    int wr = wid >> 1, wc = wid & 1;
    int l16 = lane & 15, lhi = lane >> 4;

    __shared__ __align__(16) unsigned short B_lds[32 * 512];  // 32 KB
    __shared__ float wsum[4];

    // stage B tile: 32 x 1KB chunks; wave wid stages chunks [wid*8, wid*8+8)
    #pragma unroll
    for (int c0 = 0; c0 < 8; ++c0) {
        int c = wid * 8 + c0;
        gload_lds16((const char*)Xbf + ((size_t)(tj * 32 + c)) * 1024 + lane * 16,
                    (char*)B_lds + (size_t)c * 1024);
    }
    __syncthreads();

    const bf16x8* Xs8 = (const bf16x8*)Xbf;   // fragment f at Xs8[f*64 + lane]
    const bf16x8* L   = (const bf16x8*)B_lds;

    f32x4 acc[4][4] = {};
    #pragma unroll
    for (int kk = 0; kk < 4; ++kk) {
        bf16x8 a[4], b[4];
        #pragma unroll
        for (int m = 0; m < 4; ++m)   // A from global (L2-hot, coalesced 1KB)
            a[m] = Xs8[(size_t)((ti * 8 + wr * 4 + m) * 4 + kk) * 64 + lane];
        #pragma unroll
        for (int n = 0; n < 4; ++n)   // B from LDS (contiguous ds_read_b128)
            b[n] = L[((wc * 4 + n) * 4 + kk) * 64 + lane];
        #pragma unroll
        for (int m = 0; m < 4; ++m)
            #pragma unroll
            for (int n = 0; n < 4; ++n)
                acc[m][n] = __builtin_amdgcn_mfma_f32_16x16x32_bf16(
                    a[m], b[n], acc[m][n], 0, 0, 0);
    }

    int ibase = ti * 128 + wr * 64;
    int jbase = tj * 128 + wc * 64;

    // norms loaded after MFMA loop to keep peak VGPR under the 128 cap
    float si[4][4];
    #pragma unroll
    for (int m = 0; m < 4; ++m)
        #pragma unroll
        for (int r = 0; r < 4; ++r)
            si[m][r] = sq[ibase + m * 16 + lhi * 4 + r];
    float sqj[4];
    #pragma unroll
    for (int n = 0; n < 4; ++n) sqj[n] = sq[jbase + n * 16 + l16];

    float p0 = 0.0f, p1 = 0.0f, p2 = 0.0f, p3 = 0.0f;
    #pragma unroll
    for (int m = 0; m < 4; ++m) {
        #pragma unroll
        for (int n = 0; n < 4; ++n) {
            float d2_0 = fmaf(-2.0f, acc[m][n][0], si[m][0] + sqj[n]);
            float d2_1 = fmaf(-2.0f, acc[m][n][1], si[m][1] + sqj[n]);
            float d2_2 = fmaf(-2.0f, acc[m][n][2], si[m][2] + sqj[n]);
            float d2_3 = fmaf(-2.0f, acc[m][n][3], si[m][3] + sqj[n]);
            p0 += __builtin_amdgcn_exp2f(COEF2 * __builtin_amdgcn_sqrtf(fabsf(d2_0)));
            p1 += __builtin_amdgcn_exp2f(COEF2 * __builtin_amdgcn_sqrtf(fabsf(d2_1)));
            p2 += __builtin_amdgcn_exp2f(COEF2 * __builtin_amdgcn_sqrtf(fabsf(d2_2)));
            p3 += __builtin_amdgcn_exp2f(COEF2 * __builtin_amdgcn_sqrtf(fabsf(d2_3)));
        }
    }
    float partial = (p0 + p1) + (p2 + p3);

    #pragma unroll
    for (int m = 32; m; m >>= 1) partial += __shfl_xor(partial, m, 64);
    if (lane == 0) wsum[wid] = partial;
    __syncthreads();
    if (threadIdx.x == 0) {
        float v = (wsum[0] + wsum[1]) + (wsum[2] + wsum[3]);
        // diagonal tiles: remove the 128 i==j terms (each ~= exp(0) = 1).
        // off-diagonal tiles: mirror tile (tj, ti) not computed -> double.
        if (ti == tj) v -= 128.0f; else v *= 2.0f;
        // fire-and-forget device-scope RMW; no fence, no return value.
        atomicAdd(out, v);
    }
}

extern "C" void kernel_launch(void* const* d_in, const int* in_sizes, int n_in,
                              void* d_out, int out_size, void* d_ws, size_t ws_size,
                              hipStream_t stream) {
    const float* in = (const float*)d_in[0];
    float* out = (float*)d_out;

    // workspace layout: Xs (2 MB) | sq (32 KB)
    unsigned short* Xbf = (unsigned short*)d_ws;
    float* sq = (float*)((char*)d_ws + (size_t)N_KP * KDIM * 2);

    hipMemsetAsync(out, 0, sizeof(float), stream);
    prep_kernel<<<N_KP / 16, 256, 0, stream>>>(in, Xbf, sq);
    pair_kernel<<<NTILES, 256, 0, stream>>>(Xbf, sq, out);
}

// Round 14
// 34.444 us; speedup vs baseline: 1.4211x; 1.4211x over previous
//
#include <hip/hip_runtime.h>
#include <hip/hip_bf16.h>

// loss_separation: X[n, b*2+c] = keypoints[b, n, c], N=8192 rows, K=128 cols.
// loss = sum_{i != j} exp(-0.4 * ||X_i - X_j||)
// Round 14: R12's decoupled 1-wave/64x64-tile structure, but with the
// REGISTER CAP LIFTED: launch_bounds(64,2) -> 256 VGPR. Every prior pair
// variant (incl. R7/R12) had min-waves=4 -> 128-VGPR cap -> compiler forced
// to roll the K-loop as {8 loads -> ~300cyc wait -> 16 MFMA} x4, exposing
// ~1000 cyc/wave of load-wait. Here ALL 32 fragments + norms are loaded in
// one up-front batch (~230 VGPR live), so one wait covers everything and
// the 1800-cyc epilogue keeps the SIMD busy at just 2 waves/SIMD.
// No LDS, no barriers, no atomics (R8/R13: coherent traffic = 15-20us tax).

#define N_KP   8192
#define KDIM   128          // B*C = 64*2
#define NT2    128          // number of 64-row tiles
#define NTILES2 (NT2 * (NT2 + 1) / 2)   // 8256 upper-tri 64x64 tiles
#define COEF2  (-0.57707801635558535f)   // -0.4 * log2(e)

typedef __attribute__((ext_vector_type(8))) short bf16x8;
typedef __attribute__((ext_vector_type(4))) float f32x4;

// Swizzled X layout (ushort units): fragment f = (rowblk16*4 + kk) holds the
// MFMA A/B fragment for rows [rowblk16*16, +16), k in [kk*32, +32):
//   Xs[f*512 + slot*8 + e], slot = (lane>>4)*16 + (lane&15)
//   = X[rowblk16*16 + (lane&15)][kk*32 + (lane>>4)*8 + e]
// One fragment = 1 KB, contiguous. A 64-row tile t = rowblk16 in [t*4, t*4+4).

__device__ __forceinline__ unsigned short f2bf(float f) {
    unsigned int u = __builtin_bit_cast(unsigned int, f);
    unsigned int r = (u + 0x7FFFu + ((u >> 16) & 1u)) >> 16;
    return (unsigned short)r;
}

__device__ __forceinline__ float bf2f(unsigned short u) {
    unsigned int x = ((unsigned int)u) << 16;
    return __builtin_bit_cast(float, x);
}

// 512 blocks x 256 threads; block handles 16 keypoints, thread handles 4 b's.
__global__ __launch_bounds__(256) void prep_kernel(
        const float* __restrict__ in, unsigned short* __restrict__ Xbf,
        float* __restrict__ sq) {
    int tid = threadIdx.x;
    int bt = tid >> 4, nl = tid & 15;       // 16 b-groups x 16 keypoints
    int n = blockIdx.x * 16 + nl;
    int t16 = n >> 4, l16 = n & 15;
    unsigned int* dst = (unsigned int*)Xbf;
    float s = 0.0f;
    #pragma unroll
    for (int q = 0; q < 4; ++q) {
        int b = bt * 4 + q;
        float2 v = *(const float2*)(in + (size_t)b * (N_KP * 2) + n * 2);
        unsigned short h0 = f2bf(v.x);
        unsigned short h1 = f2bf(v.y);
        float f0 = bf2f(h0), f1 = bf2f(h1);
        s = fmaf(f0, f0, s);
        s = fmaf(f1, f1, s);
        // k = 2b (+c): kk = b>>4, lhi = (b>>2)&3, e = (b&3)*2
        unsigned int off_us = (((unsigned)(t16 * 4 + (b >> 4)) * 64
                                + ((b >> 2) & 3) * 16 + l16) << 3) + ((b & 3) << 1);
        dst[off_us >> 1] = ((unsigned int)h1 << 16) | h0;
    }
    __shared__ float wsq[256];
    wsq[tid] = s;                            // [bt][nl]
    __syncthreads();
    if (tid < 16) {
        float t = 0.0f;
        #pragma unroll
        for (int pp = 0; pp < 16; ++pp) t += wsq[pp * 16 + tid];
        sq[blockIdx.x * 16 + tid] = t;
    }
}

__global__ __launch_bounds__(64, 2) void pair_kernel(
        const unsigned short* __restrict__ Xbf, const float* __restrict__ sq,
        float* __restrict__ partials) {
    int bid = blockIdx.x;
    // decode (ti, tj), ti <= tj over NT2=128: off(t) = t*(257-t)/2.
    int ti = (int)((257.0f - sqrtf(257.0f * 257.0f - 8.0f * (float)bid)) * 0.5f);
    while (ti > 0 && ti * (257 - ti) / 2 > bid) --ti;
    while ((ti + 1) * (257 - (ti + 1)) / 2 <= bid) ++ti;
    int tj = ti + (bid - ti * (257 - ti) / 2);

    int lane = threadIdx.x & 63;
    int l16 = lane & 15, lhi = lane >> 4;

    const bf16x8* Xs8 = (const bf16x8*)Xbf;   // fragment f at Xs8[f*64 + lane]

    // ---- one up-front load batch: all 32 fragments + all norms ----
    bf16x8 a[4][4], b[4][4];    // [m or n][kk] : 128 VGPRs
    #pragma unroll
    for (int m = 0; m < 4; ++m)
        #pragma unroll
        for (int kk = 0; kk < 4; ++kk)
            a[m][kk] = Xs8[(size_t)((ti * 4 + m) * 4 + kk) * 64 + lane];
    #pragma unroll
    for (int n = 0; n < 4; ++n)
        #pragma unroll
        for (int kk = 0; kk < 4; ++kk)
            b[n][kk] = Xs8[(size_t)((tj * 4 + n) * 4 + kk) * 64 + lane];

    int ibase = ti * 64;
    int jbase = tj * 64;
    float si[4][4];
    #pragma unroll
    for (int m = 0; m < 4; ++m)
        #pragma unroll
        for (int r = 0; r < 4; ++r)
            si[m][r] = sq[ibase + m * 16 + lhi * 4 + r];
    float sqj[4];
    #pragma unroll
    for (int n = 0; n < 4; ++n) sqj[n] = sq[jbase + n * 16 + l16];

    // ---- MFMA block (single vmcnt window covers all loads above) ----
    f32x4 acc[4][4] = {};
    #pragma unroll
    for (int kk = 0; kk < 4; ++kk)
        #pragma unroll
        for (int m = 0; m < 4; ++m)
            #pragma unroll
            for (int n = 0; n < 4; ++n)
                acc[m][n] = __builtin_amdgcn_mfma_f32_16x16x32_bf16(
                    a[m][kk], b[n][kk], acc[m][n], 0, 0, 0);

    // ---- epilogue: d2 = si + sqj - 2*dot -> exp2(COEF2 * sqrt(d2)) ----
    float p0 = 0.0f, p1 = 0.0f, p2 = 0.0f, p3 = 0.0f;
    #pragma unroll
    for (int m = 0; m < 4; ++m) {
        #pragma unroll
        for (int n = 0; n < 4; ++n) {
            float d2_0 = fmaf(-2.0f, acc[m][n][0], si[m][0] + sqj[n]);
            float d2_1 = fmaf(-2.0f, acc[m][n][1], si[m][1] + sqj[n]);
            float d2_2 = fmaf(-2.0f, acc[m][n][2], si[m][2] + sqj[n]);
            float d2_3 = fmaf(-2.0f, acc[m][n][3], si[m][3] + sqj[n]);
            p0 += __builtin_amdgcn_exp2f(COEF2 * __builtin_amdgcn_sqrtf(fabsf(d2_0)));
            p1 += __builtin_amdgcn_exp2f(COEF2 * __builtin_amdgcn_sqrtf(fabsf(d2_1)));
            p2 += __builtin_amdgcn_exp2f(COEF2 * __builtin_amdgcn_sqrtf(fabsf(d2_2)));
            p3 += __builtin_amdgcn_exp2f(COEF2 * __builtin_amdgcn_sqrtf(fabsf(d2_3)));
        }
    }
    float partial = (p0 + p1) + (p2 + p3);

    #pragma unroll
    for (int m = 32; m; m >>= 1) partial += __shfl_xor(partial, m, 64);
    if (lane == 0) {
        // diagonal tiles carry 64 i==j terms (~1.0 each); off-diagonal tiles
        // represent the mirror (tj,ti) too -> double.
        float v = (ti == tj) ? (partial - 64.0f) : (2.0f * partial);
        partials[bid] = v;
    }
}

__global__ __launch_bounds__(1024) void reduce_kernel(
        const float* __restrict__ partials, float* __restrict__ out) {
    float s = 0.0f;
    for (int i = threadIdx.x; i < NTILES2; i += 1024) s += partials[i];
    #pragma unroll
    for (int m = 32; m; m >>= 1) s += __shfl_xor(s, m, 64);
    __shared__ float wsum[16];
    int wid = threadIdx.x >> 6, lane = threadIdx.x & 63;
    if (lane == 0) wsum[wid] = s;
    __syncthreads();
    if (threadIdx.x == 0) {
        float t = 0.0f;
        #pragma unroll
        for (int w = 0; w < 16; ++w) t += wsum[w];
        out[0] = t;
    }
}

extern "C" void kernel_launch(void* const* d_in, const int* in_sizes, int n_in,
                              void* d_out, int out_size, void* d_ws, size_t ws_size,
                              hipStream_t stream) {
    const float* in = (const float*)d_in[0];
    float* out = (float*)d_out;

    // workspace layout: Xs (2 MB) | sq (32 KB) | partials (NTILES2*4 B)
    unsigned short* Xbf = (unsigned short*)d_ws;
    float* sq = (float*)((char*)d_ws + (size_t)N_KP * KDIM * 2);
    float* partials = (float*)((char*)d_ws + (size_t)N_KP * KDIM * 2
                               + (size_t)N_KP * 4);

    prep_kernel<<<N_KP / 16, 256, 0, stream>>>(in, Xbf, sq);
    pair_kernel<<<NTILES2, 64, 0, stream>>>(Xbf, sq, partials);
    reduce_kernel<<<1, 1024, 0, stream>>>(partials, out);
}

// Round 15
// 31.331 us; speedup vs baseline: 1.5623x; 1.0994x over previous
//
#include <hip/hip_runtime.h>
#include <hip/hip_bf16.h>

// loss_separation: X[n, b*2+c] = keypoints[b, n, c], N=8192 rows, K=128 cols.
// loss = sum_{i != j} exp(-0.4 * ||X_i - X_j||)
// Round 15 = consolidation: R7 pair (best, 31.9us) + A-prefetch (R8's loop
// body, never cleanly measured: R8 poisoned by atomics, R9 by spills) +
// prep-512 (validated). Separate reduce kernel (atomic/fence paths cost
// 15-20us on this chip: R8/R13). No cap below 4 blocks/CU (R11 spill).

#define N_KP   8192
#define KDIM   128          // B*C = 64*2
#define NT     64           // number of 128-row tiles
#define NTILES (NT * (NT + 1) / 2)   // 2080 upper-tri tiles
#define COEF2  (-0.57707801635558535f)   // -0.4 * log2(e)

typedef __attribute__((ext_vector_type(8))) short bf16x8;
typedef __attribute__((ext_vector_type(4))) float f32x4;

// Swizzled X layout (ushort units): fragment f = (rowblk16*4 + kk) holds the
// MFMA A/B fragment for rows [rowblk16*16, +16), k in [kk*32, +32):
//   Xs[f*512 + slot*8 + e], slot = (lane>>4)*16 + (lane&15)
//   = X[rowblk16*16 + (lane&15)][kk*32 + (lane>>4)*8 + e]
// One fragment = 1 KB, contiguous. A 128-row tile t = fragments [t*32, t*32+32).

__device__ __forceinline__ unsigned short f2bf(float f) {
    unsigned int u = __builtin_bit_cast(unsigned int, f);
    unsigned int r = (u + 0x7FFFu + ((u >> 16) & 1u)) >> 16;
    return (unsigned short)r;
}

__device__ __forceinline__ float bf2f(unsigned short u) {
    unsigned int x = ((unsigned int)u) << 16;
    return __builtin_bit_cast(float, x);
}

__device__ __forceinline__ void gload_lds16(const void* g, void* l) {
    __builtin_amdgcn_global_load_lds(
        (const __attribute__((address_space(1))) unsigned int*)g,
        (__attribute__((address_space(3))) unsigned int*)l, 16, 0, 0);
}

// 512 blocks x 256 threads; block handles 16 keypoints, thread handles 4 b's.
__global__ __launch_bounds__(256) void prep_kernel(
        const float* __restrict__ in, unsigned short* __restrict__ Xbf,
        float* __restrict__ sq) {
    int tid = threadIdx.x;
    int bt = tid >> 4, nl = tid & 15;       // 16 b-groups x 16 keypoints
    int n = blockIdx.x * 16 + nl;
    int t16 = n >> 4, l16 = n & 15;
    unsigned int* dst = (unsigned int*)Xbf;
    float s = 0.0f;
    #pragma unroll
    for (int q = 0; q < 4; ++q) {
        int b = bt * 4 + q;
        float2 v = *(const float2*)(in + (size_t)b * (N_KP * 2) + n * 2);
        unsigned short h0 = f2bf(v.x);
        unsigned short h1 = f2bf(v.y);
        float f0 = bf2f(h0), f1 = bf2f(h1);
        s = fmaf(f0, f0, s);
        s = fmaf(f1, f1, s);
        // k = 2b (+c): kk = b>>4, lhi = (b>>2)&3, e = (b&3)*2
        unsigned int off_us = (((unsigned)(t16 * 4 + (b >> 4)) * 64
                                + ((b >> 2) & 3) * 16 + l16) << 3) + ((b & 3) << 1);
        dst[off_us >> 1] = ((unsigned int)h1 << 16) | h0;
    }
    __shared__ float wsq[256];
    wsq[tid] = s;                            // [bt][nl]
    __syncthreads();
    if (tid < 16) {
        float t = 0.0f;
        #pragma unroll
        for (int pp = 0; pp < 16; ++pp) t += wsq[pp * 16 + tid];
        sq[blockIdx.x * 16 + tid] = t;
    }
}

__global__ __launch_bounds__(256, 4) void pair_kernel(
        const unsigned short* __restrict__ Xbf, const float* __restrict__ sq,
        float* __restrict__ partials) {
    int bid = blockIdx.x;
    // decode (ti, tj), ti <= tj: off(t) = t*(129-t)/2 tiles precede row t.
    int ti = (int)((129.0f - sqrtf(129.0f * 129.0f - 8.0f * (float)bid)) * 0.5f);
    while (ti > 0 && ti * (129 - ti) / 2 > bid) --ti;
    while ((ti + 1) * (129 - (ti + 1)) / 2 <= bid) ++ti;
    int tj = ti + (bid - ti * (129 - ti) / 2);

    int wid  = threadIdx.x >> 6;
    int lane = threadIdx.x & 63;
    int wr = wid >> 1, wc = wid & 1;
    int l16 = lane & 15, lhi = lane >> 4;

    __shared__ __align__(16) unsigned short B_lds[32 * 512];  // 32 KB
    __shared__ float wsum[4];

    const bf16x8* Xs8 = (const bf16x8*)Xbf;   // fragment f at Xs8[f*64 + lane]

    // issue kk=0 A-fragment loads BEFORE staging: the vmcnt(0) drain at the
    // barrier makes them ready for free.
    bf16x8 aN[4];
    #pragma unroll
    for (int m = 0; m < 4; ++m)
        aN[m] = Xs8[(size_t)((ti * 8 + wr * 4 + m) * 4 + 0) * 64 + lane];

    // stage B tile: 32 x 1KB chunks; wave wid stages chunks [wid*8, wid*8+8)
    #pragma unroll
    for (int c0 = 0; c0 < 8; ++c0) {
        int c = wid * 8 + c0;
        gload_lds16((const char*)Xbf + ((size_t)(tj * 32 + c)) * 1024 + lane * 16,
                    (char*)B_lds + (size_t)c * 1024);
    }
    __syncthreads();

    const bf16x8* L = (const bf16x8*)B_lds;

    f32x4 acc[4][4] = {};
    #pragma unroll
    for (int kk = 0; kk < 4; ++kk) {
        bf16x8 aC[4];
        #pragma unroll
        for (int m = 0; m < 4; ++m) aC[m] = aN[m];
        if (kk < 3) {   // prefetch next kk's A under this kk's MFMAs
            #pragma unroll
            for (int m = 0; m < 4; ++m)
                aN[m] = Xs8[(size_t)((ti * 8 + wr * 4 + m) * 4 + kk + 1) * 64 + lane];
        }
        bf16x8 b[4];
        #pragma unroll
        for (int n = 0; n < 4; ++n)   // B from LDS (contiguous ds_read_b128)
            b[n] = L[((wc * 4 + n) * 4 + kk) * 64 + lane];
        #pragma unroll
        for (int m = 0; m < 4; ++m)
            #pragma unroll
            for (int n = 0; n < 4; ++n)
                acc[m][n] = __builtin_amdgcn_mfma_f32_16x16x32_bf16(
                    aC[m], b[n], acc[m][n], 0, 0, 0);
    }

    int ibase = ti * 128 + wr * 64;
    int jbase = tj * 128 + wc * 64;

    float si[4][4];
    #pragma unroll
    for (int m = 0; m < 4; ++m)
        #pragma unroll
        for (int r = 0; r < 4; ++r)
            si[m][r] = sq[ibase + m * 16 + lhi * 4 + r];
    float sqj[4];
    #pragma unroll
    for (int n = 0; n < 4; ++n) sqj[n] = sq[jbase + n * 16 + l16];

    float p0 = 0.0f, p1 = 0.0f, p2 = 0.0f, p3 = 0.0f;
    #pragma unroll
    for (int m = 0; m < 4; ++m) {
        #pragma unroll
        for (int n = 0; n < 4; ++n) {
            float d2_0 = fmaf(-2.0f, acc[m][n][0], si[m][0] + sqj[n]);
            float d2_1 = fmaf(-2.0f, acc[m][n][1], si[m][1] + sqj[n]);
            float d2_2 = fmaf(-2.0f, acc[m][n][2], si[m][2] + sqj[n]);
            float d2_3 = fmaf(-2.0f, acc[m][n][3], si[m][3] + sqj[n]);
            p0 += __builtin_amdgcn_exp2f(COEF2 * __builtin_amdgcn_sqrtf(fabsf(d2_0)));
            p1 += __builtin_amdgcn_exp2f(COEF2 * __builtin_amdgcn_sqrtf(fabsf(d2_1)));
            p2 += __builtin_amdgcn_exp2f(COEF2 * __builtin_amdgcn_sqrtf(fabsf(d2_2)));
            p3 += __builtin_amdgcn_exp2f(COEF2 * __builtin_amdgcn_sqrtf(fabsf(d2_3)));
        }
    }
    float partial = (p0 + p1) + (p2 + p3);

    #pragma unroll
    for (int m = 32; m; m >>= 1) partial += __shfl_xor(partial, m, 64);
    if (lane == 0) wsum[wid] = partial;
    __syncthreads();
    if (threadIdx.x == 0) {
        float v = (wsum[0] + wsum[1]) + (wsum[2] + wsum[3]);
        // diagonal tiles: remove the 128 i==j terms (each ~= exp(0) = 1).
        // off-diagonal tiles: mirror tile (tj, ti) not computed -> double.
        if (ti == tj) v -= 128.0f; else v *= 2.0f;
        partials[bid] = v;
    }
}

__global__ __launch_bounds__(256) void reduce_kernel(
        const float* __restrict__ partials, float* __restrict__ out) {
    float s = 0.0f;
    for (int i = threadIdx.x; i < NTILES; i += 256) s += partials[i];
    #pragma unroll
    for (int m = 32; m; m >>= 1) s += __shfl_xor(s, m, 64);
    __shared__ float wsum[4];
    int wid = threadIdx.x >> 6, lane = threadIdx.x & 63;
    if (lane == 0) wsum[wid] = s;
    __syncthreads();
    if (threadIdx.x == 0) out[0] = (wsum[0] + wsum[1]) + (wsum[2] + wsum[3]);
}

extern "C" void kernel_launch(void* const* d_in, const int* in_sizes, int n_in,
                              void* d_out, int out_size, void* d_ws, size_t ws_size,
                              hipStream_t stream) {
    const float* in = (const float*)d_in[0];
    float* out = (float*)d_out;

    // workspace layout: Xs (2 MB) | sq (32 KB) | partials (NTILES*4 B)
    unsigned short* Xbf = (unsigned short*)d_ws;
    float* sq = (float*)((char*)d_ws + (size_t)N_KP * KDIM * 2);
    float* partials = (float*)((char*)d_ws + (size_t)N_KP * KDIM * 2
                               + (size_t)N_KP * 4);

    prep_kernel<<<N_KP / 16, 256, 0, stream>>>(in, Xbf, sq);
    pair_kernel<<<NTILES, 256, 0, stream>>>(Xbf, sq, partials);
    reduce_kernel<<<1, 256, 0, stream>>>(partials, out);
}